// Round 1
// baseline (148.544 us; speedup 1.0000x reference)
//
#include <hip/hip_runtime.h>
#include <math.h>

#define NTOT 16384
#define KK 16
#define DD 16
#define NPAIR 136   // upper-tri incl diag of 16x16

// ---- ws layout (bytes), all written every call before being read ----
#define WS_SIG   0          // float[16*256]  Sigma_k (lower entries valid)   kA->kB
#define WS_AF    16384      // float[16*256]  A_k (lower entries valid)       kA->kB
#define WS_RHS   32768      // float[16*16]   rhs_k = Sigma_k mu_k            kA->kB,main
#define WS_WP    33792      // float[16*136]  W_k packed lower (Sigma=W^T W)  kA->main
#define WS_LCS   42496      // float[136]     lC packed upper (+ln2 offdiag)  kB->main
#define WS_PART  43040      // double[256]    block partial sums              main->fin
#define WS_END   45088

#define LN2PI 1.8378770664093454836f

// ---------------- kernel A: per-component precompute ----------------
__global__ void gm_kA(const float* __restrict__ mu, const float* __restrict__ L,
                      char* __restrict__ wsb) {
  int k = threadIdx.x;
  if (k >= KK) return;
  const float* Lk = L + k * DD * DD;

  // A = tril(L) tril(L)^T + I, packed lower
  float Af[NPAIR];
  for (int a = 0; a < DD; a++) {
    int ab = a * (a + 1) / 2;
    for (int c = 0; c <= a; c++) {
      float s = (a == c) ? 1.0f : 0.0f;
      for (int b = 0; b <= c; b++)   // tril: min(a,c)=c
        s += Lk[a * DD + b] * Lk[c * DD + b];
      Af[ab + c] = s;
    }
  }
  // store A (lower) full-layout for kB
  float* Aout = (float*)(wsb + WS_AF) + k * DD * DD;
  for (int a = 0; a < DD; a++)
    for (int c = 0; c <= a; c++)
      Aout[a * DD + c] = Af[a * (a + 1) / 2 + c];

  // Cholesky A = G G^T in place (packed lower)
  for (int c = 0; c < DD; c++) {
    int cb = c * (c + 1) / 2;
    float s = Af[cb + c];
    for (int m = 0; m < c; m++) { float v = Af[cb + m]; s -= v * v; }
    float dd = sqrtf(s);
    Af[cb + c] = dd;
    float inv = 1.0f / dd;
    for (int r = c + 1; r < DD; r++) {
      int rb = r * (r + 1) / 2;
      float u = Af[rb + c];
      for (int m = 0; m < c; m++) u -= Af[rb + m] * Af[cb + m];
      Af[rb + c] = u * inv;
    }
  }
  // W = G^{-1} (packed lower); Sigma = W^T W
  float Wf[NPAIR];
  for (int c = 0; c < DD; c++) {
    Wf[c * (c + 1) / 2 + c] = 1.0f / Af[c * (c + 1) / 2 + c];
    for (int r = c + 1; r < DD; r++) {
      int rb = r * (r + 1) / 2;
      float s = 0.0f;
      for (int m = c; m < r; m++) s += Af[rb + m] * Wf[m * (m + 1) / 2 + c];
      Wf[rb + c] = -s / Af[rb + r];
    }
  }
  // Sigma full (need full rows for rhs)
  float Sg[DD * DD];
  for (int d0 = 0; d0 < DD; d0++) {
    for (int e = d0; e < DD; e++) {
      float s = 0.0f;
      for (int r = e; r < DD; r++)
        s += Wf[r * (r + 1) / 2 + d0] * Wf[r * (r + 1) / 2 + e];
      Sg[d0 * DD + e] = s; Sg[e * DD + d0] = s;
    }
  }
  float* Sout = (float*)(wsb + WS_SIG) + k * DD * DD;
  for (int a = 0; a < DD; a++)
    for (int c = 0; c <= a; c++)
      Sout[a * DD + c] = Sg[a * DD + c];

  const float* muk = mu + k * DD;
  float* Rout = (float*)(wsb + WS_RHS) + k * DD;
  for (int d0 = 0; d0 < DD; d0++) {
    float s = 0.0f;
    for (int e = 0; e < DD; e++) s += Sg[d0 * DD + e] * muk[e];
    Rout[d0] = s;
  }
  float* Wout = (float*)(wsb + WS_WP) + k * NPAIR;
  for (int p = 0; p < NPAIR; p++) Wout[p] = Wf[p];
}

// ---------------- kernel B: per-pair constants ----------------
__device__ __forceinline__ float chol_packed_ldet(float* Mx) {
  float ldet = 0.0f;
  for (int c = 0; c < DD; c++) {
    int cb = c * (c + 1) / 2;
    float s = Mx[cb + c];
    for (int m = 0; m < c; m++) { float v = Mx[cb + m]; s -= v * v; }
    float dd = sqrtf(s);
    Mx[cb + c] = dd;
    ldet += logf(dd);
    float inv = 1.0f / dd;
    for (int r = c + 1; r < DD; r++) {
      int rb = r * (r + 1) / 2;
      float u = Mx[rb + c];
      for (int m = 0; m < c; m++) u -= Mx[rb + m] * Mx[cb + m];
      Mx[rb + c] = u * inv;
    }
  }
  return 2.0f * ldet;
}

__global__ void gm_kB(const float* __restrict__ mu, const float* __restrict__ wts,
                      char* __restrict__ wsb) {
  int t = blockIdx.x * blockDim.x + threadIdx.x;
  if (t >= 256) return;
  int i = t >> 4, j = t & 15;
  if (j < i) return;

  const float* Sf = (const float*)(wsb + WS_SIG);
  const float* Af = (const float*)(wsb + WS_AF);
  const float* Rf = (const float*)(wsb + WS_RHS);

  float Mx[NPAIR];
  // --- Ssum = Sigma_i + Sigma_j ---
  {
    const float* Si = Sf + i * 256; const float* Sj = Sf + j * 256;
    for (int a = 0; a < DD; a++) {
      int ab = a * (a + 1) / 2;
      for (int c = 0; c <= a; c++) Mx[ab + c] = Si[a * DD + c] + Sj[a * DD + c];
    }
  }
  float ldetS = chol_packed_ldet(Mx);
  float yv[DD]; float cq = 0.0f;
  for (int r = 0; r < DD; r++) {
    int rb = r * (r + 1) / 2;
    float s = Rf[i * DD + r] + Rf[j * DD + r];
    for (int m = 0; m < r; m++) s -= Mx[rb + m] * yv[m];
    float v = s / Mx[rb + r];
    yv[r] = v; cq += v * v;
  }
  // --- Asum = A_i + A_j ---
  {
    const float* Ai = Af + i * 256; const float* Aj = Af + j * 256;
    for (int a = 0; a < DD; a++) {
      int ab = a * (a + 1) / 2;
      for (int c = 0; c <= a; c++) Mx[ab + c] = Ai[a * DD + c] + Aj[a * DD + c];
    }
  }
  float ldetA = chol_packed_ldet(Mx);
  float q = 0.0f;
  for (int r = 0; r < DD; r++) {
    int rb = r * (r + 1) / 2;
    float s = mu[i * DD + r] - mu[j * DD + r];
    for (int m = 0; m < r; m++) s -= Mx[rb + m] * yv[m];
    float v = s / Mx[rb + r];
    yv[r] = v; q += v * v;
  }

  float lC = -0.5f * q - 0.5f * ldetA + 0.5f * ldetS - (float)DD * LN2PI
             + logf(wts[i]) + logf(wts[j]) - 0.5f * cq;
  if (i < j) lC += 0.69314718056f;   // symmetric pair counted twice

  int p = i * DD - (i * (i - 1)) / 2 + (j - i);
  ((float*)(wsb + WS_LCS))[p] = lC;
}

// ---------------- main kernel: per-sample log pdf ----------------
__global__ __launch_bounds__(64) void gm_main(const float* __restrict__ X,
                                              char* __restrict__ wsb) {
  __shared__ float sW[KK * NPAIR];
  __shared__ float sR[KK * DD];
  __shared__ float sLC[NPAIR];
  __shared__ float sE[64][17];

  int tid = threadIdx.x;
  {
    const float* Wp = (const float*)(wsb + WS_WP);
    const float* Rf = (const float*)(wsb + WS_RHS);
    const float* lc = (const float*)(wsb + WS_LCS);
    for (int idx = tid; idx < KK * NPAIR; idx += 64) sW[idx] = Wp[idx];
    for (int idx = tid; idx < KK * DD; idx += 64) sR[idx] = Rf[idx];
    for (int idx = tid; idx < NPAIR; idx += 64) sLC[idx] = lc[idx];
  }
  __syncthreads();

  int n = blockIdx.x * 64 + tid;
  const float4* Xp = (const float4*)(X + (size_t)n * DD);
  float4 a0 = Xp[0], a1 = Xp[1], a2 = Xp[2], a3 = Xp[3];
  float x[16] = {a0.x, a0.y, a0.z, a0.w, a1.x, a1.y, a1.z, a1.w,
                 a2.x, a2.y, a2.z, a2.w, a3.x, a3.y, a3.z, a3.w};

  for (int k = 0; k < KK; k++) {
    const float* Wk = &sW[k * NPAIR];
    float g = 0.0f;
    #pragma unroll
    for (int r = 0; r < DD; r++) {
      float y = 0.0f;
      const int base = r * (r + 1) / 2;
      #pragma unroll
      for (int c = 0; c <= r; c++) y = fmaf(Wk[base + c], x[c], y);
      g = fmaf(y, y, g);
    }
    float h = 0.0f;
    #pragma unroll
    for (int d = 0; d < DD; d++) h = fmaf(sR[k * DD + d], x[d], h);
    sE[tid][k] = fmaf(-0.5f, g, h);   // e_k = h - g/2
  }

  // pass 1: max exponent
  float T = -3.0e38f;
  {
    int p = 0;
    for (int i = 0; i < KK; i++) {
      float ei = sE[tid][i];
      for (int j = i; j < KK; j++) {
        float t = sLC[p++] + ei + sE[tid][j];
        T = fmaxf(T, t);
      }
    }
  }
  // pass 2: sum
  float s = 0.0f;
  {
    int p = 0;
    for (int i = 0; i < KK; i++) {
      float ei = sE[tid][i] - T;
      for (int j = i; j < KK; j++) {
        s += __expf(sLC[p++] + ei + sE[tid][j]);
      }
    }
  }
  float lp = T + __logf(s);

  double d = (double)lp;
  #pragma unroll
  for (int off = 32; off > 0; off >>= 1) d += __shfl_down(d, off);
  if (tid == 0) ((double*)(wsb + WS_PART))[blockIdx.x] = d;
}

// ---------------- finalize ----------------
__global__ void gm_fin(const double* __restrict__ part, float* __restrict__ out) {
  int t = threadIdx.x;
  double v = part[t];
  #pragma unroll
  for (int off = 32; off > 0; off >>= 1) v += __shfl_down(v, off);
  __shared__ double r4[4];
  if ((t & 63) == 0) r4[t >> 6] = v;
  __syncthreads();
  if (t == 0) out[0] = (float)((r4[0] + r4[1] + r4[2] + r4[3]) * (1.0 / 16384.0));
}

extern "C" void kernel_launch(void* const* d_in, const int* in_sizes, int n_in,
                              void* d_out, int out_size, void* d_ws, size_t ws_size,
                              hipStream_t stream) {
  const float* X   = (const float*)d_in[0];
  const float* mu  = (const float*)d_in[1];
  const float* L   = (const float*)d_in[2];
  const float* wts = (const float*)d_in[3];
  char* wsb = (char*)d_ws;
  if (ws_size < WS_END) return;

  hipLaunchKernelGGL(gm_kA, dim3(1), dim3(64), 0, stream, mu, L, wsb);
  hipLaunchKernelGGL(gm_kB, dim3(4), dim3(64), 0, stream, mu, wts, wsb);
  hipLaunchKernelGGL(gm_main, dim3(NTOT / 64), dim3(64), 0, stream, X, wsb);
  hipLaunchKernelGGL(gm_fin, dim3(1), dim3(256), 0, stream,
                     (const double*)(wsb + WS_PART), (float*)d_out);
}

// Round 2
// 57.551 us; speedup vs baseline: 2.5811x; 2.5811x over previous
//
#include <hip/hip_runtime.h>
#include <math.h>

#define NTOT 16384
#define KK 16
#define DD 16
#define NPAIR 136   // upper-tri incl diag of 16x16

// ---- ws layout (bytes), all written every call before being read ----
#define WS_SIG   0          // float[16*256]  Sigma_k (lower entries valid)   kA->kB
#define WS_AF    16384      // float[16*256]  A_k (lower entries valid)       kA->kB
#define WS_RHS   32768      // float[16*16]   rhs_k = Sigma_k mu_k            kA->kB,main
#define WS_WP    33792      // float[16*136]  W_k packed lower (Sigma=W^T W)  kA->main
#define WS_LCS   42496      // float[136]     lC packed upper (+ln2 offdiag)  kB->main
#define WS_PART  43040      // double[256]    block partial sums              main->fin
#define WS_END   45088

#define LN2PI 1.8378770664093454836f

// ---------------- kernel A: per-component precompute ----------------
// All loops fully unrolled -> packed arrays stay in VGPRs (no scratch).
__global__ __launch_bounds__(64) void gm_kA(const float* __restrict__ mu,
                                            const float* __restrict__ L,
                                            char* __restrict__ wsb) {
  int k = threadIdx.x;
  if (k >= KK) return;
  const float* Lk = L + k * DD * DD;

  float Lr[NPAIR];                       // tril(L) packed
  #pragma unroll
  for (int a = 0; a < DD; a++)
    #pragma unroll
    for (int b = 0; b <= a; b++)
      Lr[a * (a + 1) / 2 + b] = Lk[a * DD + b];

  // A = tril(L) tril(L)^T + I, packed lower
  float Af[NPAIR];
  #pragma unroll
  for (int a = 0; a < DD; a++) {
    #pragma unroll
    for (int c = 0; c <= a; c++) {
      float s = (a == c) ? 1.0f : 0.0f;
      #pragma unroll
      for (int b = 0; b <= c; b++)
        s = fmaf(Lr[a * (a + 1) / 2 + b], Lr[c * (c + 1) / 2 + b], s);
      Af[a * (a + 1) / 2 + c] = s;
    }
  }
  // store A (lower) full-layout for kB
  {
    float* Aout = (float*)(wsb + WS_AF) + k * DD * DD;
    #pragma unroll
    for (int a = 0; a < DD; a++)
      #pragma unroll
      for (int c = 0; c <= a; c++)
        Aout[a * DD + c] = Af[a * (a + 1) / 2 + c];
  }

  // Cholesky A = G G^T in place (packed lower)
  #pragma unroll
  for (int c = 0; c < DD; c++) {
    float s = Af[c * (c + 1) / 2 + c];
    #pragma unroll
    for (int m = 0; m < c; m++) { float v = Af[c * (c + 1) / 2 + m]; s = fmaf(-v, v, s); }
    float dd = sqrtf(s);
    Af[c * (c + 1) / 2 + c] = dd;
    float inv = 1.0f / dd;
    #pragma unroll
    for (int r = c + 1; r < DD; r++) {
      float u = Af[r * (r + 1) / 2 + c];
      #pragma unroll
      for (int m = 0; m < c; m++) u = fmaf(-Af[r * (r + 1) / 2 + m], Af[c * (c + 1) / 2 + m], u);
      Af[r * (r + 1) / 2 + c] = u * inv;
    }
  }
  // W = G^{-1} (packed lower); Sigma = W^T W
  float Wf[NPAIR];
  #pragma unroll
  for (int c = 0; c < DD; c++) {
    Wf[c * (c + 1) / 2 + c] = 1.0f / Af[c * (c + 1) / 2 + c];
    #pragma unroll
    for (int r = c + 1; r < DD; r++) {
      float s = 0.0f;
      #pragma unroll
      for (int m = c; m < r; m++) s = fmaf(Af[r * (r + 1) / 2 + m], Wf[m * (m + 1) / 2 + c], s);
      Wf[r * (r + 1) / 2 + c] = -s / Af[r * (r + 1) / 2 + r];
    }
  }
  // Sigma = W^T W (lower triangle + full for rhs)
  float Sg[DD * DD];
  #pragma unroll
  for (int d0 = 0; d0 < DD; d0++) {
    #pragma unroll
    for (int e = d0; e < DD; e++) {
      float s = 0.0f;
      #pragma unroll
      for (int r = e; r < DD; r++)
        s = fmaf(Wf[r * (r + 1) / 2 + d0], Wf[r * (r + 1) / 2 + e], s);
      Sg[d0 * DD + e] = s; Sg[e * DD + d0] = s;
    }
  }
  {
    float* Sout = (float*)(wsb + WS_SIG) + k * DD * DD;
    #pragma unroll
    for (int a = 0; a < DD; a++)
      #pragma unroll
      for (int c = 0; c <= a; c++)
        Sout[a * DD + c] = Sg[a * DD + c];
  }

  const float* muk = mu + k * DD;
  float* Rout = (float*)(wsb + WS_RHS) + k * DD;
  #pragma unroll
  for (int d0 = 0; d0 < DD; d0++) {
    float s = 0.0f;
    #pragma unroll
    for (int e = 0; e < DD; e++) s = fmaf(Sg[d0 * DD + e], muk[e], s);
    Rout[d0] = s;
  }
  float* Wout = (float*)(wsb + WS_WP) + k * NPAIR;
  #pragma unroll
  for (int p = 0; p < NPAIR; p++) Wout[p] = Wf[p];
}

// ---------------- kernel B: per-pair constants ----------------
// Fully-unrolled packed Cholesky (registers only).
__device__ __forceinline__ float chol_packed_ldet(float* Mx) {
  float ldet = 0.0f;
  #pragma unroll
  for (int c = 0; c < DD; c++) {
    float s = Mx[c * (c + 1) / 2 + c];
    #pragma unroll
    for (int m = 0; m < c; m++) { float v = Mx[c * (c + 1) / 2 + m]; s = fmaf(-v, v, s); }
    float dd = sqrtf(s);
    Mx[c * (c + 1) / 2 + c] = dd;
    ldet += __logf(dd);
    float inv = 1.0f / dd;
    #pragma unroll
    for (int r = c + 1; r < DD; r++) {
      float u = Mx[r * (r + 1) / 2 + c];
      #pragma unroll
      for (int m = 0; m < c; m++)
        u = fmaf(-Mx[r * (r + 1) / 2 + m], Mx[c * (c + 1) / 2 + m], u);
      Mx[r * (r + 1) / 2 + c] = u * inv;
    }
  }
  return 2.0f * ldet;
}

__global__ __launch_bounds__(64) void gm_kB(const float* __restrict__ mu,
                                            const float* __restrict__ wts,
                                            char* __restrict__ wsb) {
  int t = blockIdx.x * blockDim.x + threadIdx.x;
  if (t >= 256) return;
  int i = t >> 4, j = t & 15;
  if (j < i) return;

  const float* Sf = (const float*)(wsb + WS_SIG);
  const float* Af = (const float*)(wsb + WS_AF);
  const float* Rf = (const float*)(wsb + WS_RHS);

  float Mx[NPAIR];
  // --- Ssum = Sigma_i + Sigma_j ---
  {
    const float* Si = Sf + i * 256; const float* Sj = Sf + j * 256;
    #pragma unroll
    for (int a = 0; a < DD; a++)
      #pragma unroll
      for (int c = 0; c <= a; c++)
        Mx[a * (a + 1) / 2 + c] = Si[a * DD + c] + Sj[a * DD + c];
  }
  float ldetS = chol_packed_ldet(Mx);
  float yv[DD]; float cq = 0.0f;
  #pragma unroll
  for (int r = 0; r < DD; r++) {
    float s = Rf[i * DD + r] + Rf[j * DD + r];
    #pragma unroll
    for (int m = 0; m < r; m++) s = fmaf(-Mx[r * (r + 1) / 2 + m], yv[m], s);
    float v = s / Mx[r * (r + 1) / 2 + r];
    yv[r] = v; cq = fmaf(v, v, cq);
  }
  // --- Asum = A_i + A_j ---
  {
    const float* Ai = Af + i * 256; const float* Aj = Af + j * 256;
    #pragma unroll
    for (int a = 0; a < DD; a++)
      #pragma unroll
      for (int c = 0; c <= a; c++)
        Mx[a * (a + 1) / 2 + c] = Ai[a * DD + c] + Aj[a * DD + c];
  }
  float ldetA = chol_packed_ldet(Mx);
  float q = 0.0f;
  #pragma unroll
  for (int r = 0; r < DD; r++) {
    float s = mu[i * DD + r] - mu[j * DD + r];
    #pragma unroll
    for (int m = 0; m < r; m++) s = fmaf(-Mx[r * (r + 1) / 2 + m], yv[m], s);
    float v = s / Mx[r * (r + 1) / 2 + r];
    yv[r] = v; q = fmaf(v, v, q);
  }

  float lC = -0.5f * q - 0.5f * ldetA + 0.5f * ldetS - (float)DD * LN2PI
             + __logf(wts[i]) + __logf(wts[j]) - 0.5f * cq;
  if (i < j) lC += 0.69314718056f;   // symmetric pair counted twice

  int p = i * DD - (i * (i - 1)) / 2 + (j - i);
  ((float*)(wsb + WS_LCS))[p] = lC;
}

// ---------------- main kernel: per-sample log pdf ----------------
__global__ __launch_bounds__(64) void gm_main(const float* __restrict__ X,
                                              char* __restrict__ wsb) {
  __shared__ float sW[KK * NPAIR];
  __shared__ float sR[KK * DD];
  __shared__ float sLC[NPAIR];
  __shared__ float sE[64][17];

  int tid = threadIdx.x;
  {
    const float* Wp = (const float*)(wsb + WS_WP);
    const float* Rf = (const float*)(wsb + WS_RHS);
    const float* lc = (const float*)(wsb + WS_LCS);
    for (int idx = tid; idx < KK * NPAIR; idx += 64) sW[idx] = Wp[idx];
    for (int idx = tid; idx < KK * DD; idx += 64) sR[idx] = Rf[idx];
    for (int idx = tid; idx < NPAIR; idx += 64) sLC[idx] = lc[idx];
  }
  __syncthreads();

  int n = blockIdx.x * 64 + tid;
  const float4* Xp = (const float4*)(X + (size_t)n * DD);
  float4 a0 = Xp[0], a1 = Xp[1], a2 = Xp[2], a3 = Xp[3];
  float x[16] = {a0.x, a0.y, a0.z, a0.w, a1.x, a1.y, a1.z, a1.w,
                 a2.x, a2.y, a2.z, a2.w, a3.x, a3.y, a3.z, a3.w};

  for (int k = 0; k < KK; k++) {
    const float* Wk = &sW[k * NPAIR];
    float g = 0.0f;
    #pragma unroll
    for (int r = 0; r < DD; r++) {
      float y = 0.0f;
      const int base = r * (r + 1) / 2;
      #pragma unroll
      for (int c = 0; c <= r; c++) y = fmaf(Wk[base + c], x[c], y);
      g = fmaf(y, y, g);
    }
    float h = 0.0f;
    #pragma unroll
    for (int d = 0; d < DD; d++) h = fmaf(sR[k * DD + d], x[d], h);
    sE[tid][k] = fmaf(-0.5f, g, h);   // e_k = h - g/2
  }

  // pass 1: max exponent
  float T = -3.0e38f;
  {
    int p = 0;
    for (int i = 0; i < KK; i++) {
      float ei = sE[tid][i];
      for (int j = i; j < KK; j++) {
        float t = sLC[p++] + ei + sE[tid][j];
        T = fmaxf(T, t);
      }
    }
  }
  // pass 2: sum
  float s = 0.0f;
  {
    int p = 0;
    for (int i = 0; i < KK; i++) {
      float ei = sE[tid][i] - T;
      for (int j = i; j < KK; j++) {
        s += __expf(sLC[p++] + ei + sE[tid][j]);
      }
    }
  }
  float lp = T + __logf(s);

  double d = (double)lp;
  #pragma unroll
  for (int off = 32; off > 0; off >>= 1) d += __shfl_down(d, off);
  if (tid == 0) ((double*)(wsb + WS_PART))[blockIdx.x] = d;
}

// ---------------- finalize ----------------
__global__ void gm_fin(const double* __restrict__ part, float* __restrict__ out) {
  int t = threadIdx.x;
  double v = part[t];
  #pragma unroll
  for (int off = 32; off > 0; off >>= 1) v += __shfl_down(v, off);
  __shared__ double r4[4];
  if ((t & 63) == 0) r4[t >> 6] = v;
  __syncthreads();
  if (t == 0) out[0] = (float)((r4[0] + r4[1] + r4[2] + r4[3]) * (1.0 / 16384.0));
}

extern "C" void kernel_launch(void* const* d_in, const int* in_sizes, int n_in,
                              void* d_out, int out_size, void* d_ws, size_t ws_size,
                              hipStream_t stream) {
  const float* X   = (const float*)d_in[0];
  const float* mu  = (const float*)d_in[1];
  const float* L   = (const float*)d_in[2];
  const float* wts = (const float*)d_in[3];
  char* wsb = (char*)d_ws;
  if (ws_size < WS_END) return;

  hipLaunchKernelGGL(gm_kA, dim3(1), dim3(64), 0, stream, mu, L, wsb);
  hipLaunchKernelGGL(gm_kB, dim3(4), dim3(64), 0, stream, mu, wts, wsb);
  hipLaunchKernelGGL(gm_main, dim3(NTOT / 64), dim3(64), 0, stream, X, wsb);
  hipLaunchKernelGGL(gm_fin, dim3(1), dim3(256), 0, stream,
                     (const double*)(wsb + WS_PART), (float*)d_out);
}

// Round 3
// 50.842 us; speedup vs baseline: 2.9216x; 1.1320x over previous
//
#include <hip/hip_runtime.h>
#include <math.h>

#define NTOT 16384
#define KK 16
#define DD 16
#define NPAIR 136   // upper-tri incl diag of 16x16

// ---- ws layout (bytes) ----
#define WS_RHS   0          // float[16*16]   rhs_k = Sigma_k mu_k            pre->main
#define WS_WP    1024       // float[16*136]  W_k packed lower (Sigma=W^T W)  pre->main
#define WS_LCS   9728       // float[136]     lC packed upper (+ln2 offdiag)  pre->main
#define WS_PART  10272      // double[256]    block partial sums              main->fin
#define WS_END   12320

#define LN2PI 1.8378770664093454836f

// ---------------- fused precompute: per-component (phase A) + per-pair (phase B) ----
// Phase A: lane-parallel. 16 lanes per component; lane r holds row r (or column r)
// of the 16x16 matrices -> ~80 VGPRs live, no scratch. Cross-row via __shfl(.,.,16).
__global__ __launch_bounds__(256) void gm_pre(const float* __restrict__ mu,
                                              const float* __restrict__ L,
                                              const float* __restrict__ wts,
                                              char* __restrict__ wsb) {
  __shared__ float sSig[KK][DD * DD];   // lower entries valid
  __shared__ float sA[KK][DD * DD];     // lower entries valid
  __shared__ float sR[KK * DD];

  const int tid = threadIdx.x;
  const int k = tid >> 4;        // component
  const int r = tid & 15;        // row (phase A part 1) / column (part 2) index

  // --- load my row of tril(L), zero-padded ---
  const float* Lk = L + k * DD * DD;
  float Lx[DD];
  #pragma unroll
  for (int b = 0; b < DD; b++) Lx[b] = (b <= r) ? Lk[r * DD + b] : 0.0f;

  // --- A row r: A[r][c] = sum_{b<=min(r,c)} L[r][b]L[c][b] + (r==c) ---
  float Ar[DD];
  #pragma unroll
  for (int c = 0; c < DD; c++) {
    float s = (r == c) ? 1.0f : 0.0f;
    #pragma unroll
    for (int b = 0; b <= c; b++)
      s = fmaf(Lx[b], __shfl(Lx[b], c, 16), s);   // Lx[b]=0 for b>r
    Ar[c] = s;
  }
  #pragma unroll
  for (int c = 0; c < DD; c++) if (c <= r) sA[k][r * DD + c] = Ar[c];

  // --- Cholesky A = G G^T, row-parallel (lane r holds G row r) ---
  float Gr[DD];
  #pragma unroll
  for (int m = 0; m < DD; m++) Gr[m] = 0.0f;
  #pragma unroll
  for (int c = 0; c < DD; c++) {
    float u = Ar[c];
    #pragma unroll
    for (int m = 0; m < c; m++)
      u = fmaf(-Gr[m], __shfl(Gr[m], c, 16), u);  // G[c][m] from lane c
    float d = sqrtf(__shfl(u, c, 16));            // uniform across group
    float val = (r == c) ? d : u / d;
    if (r >= c) Gr[c] = val;
  }

  // --- W = G^{-1}: lane r holds COLUMN r of W (fwd substitution over rows rr) ---
  float Wc[DD];
  #pragma unroll
  for (int m = 0; m < DD; m++) Wc[m] = 0.0f;
  #pragma unroll
  for (int rr = 0; rr < DD; rr++) {
    float s = (r == rr) ? 1.0f : 0.0f;
    #pragma unroll
    for (int m = 0; m < rr; m++)
      s = fmaf(-__shfl(Gr[m], rr, 16), Wc[m], s); // Wc[m]=0 for m<r kills extras
    Wc[rr] = s / __shfl(Gr[rr], rr, 16);
  }
  // store W packed row-major for gm_main (lane r = column r)
  {
    float* Wout = (float*)(wsb + WS_WP) + k * NPAIR;
    #pragma unroll
    for (int rr = 0; rr < DD; rr++)
      if (rr >= r) Wout[rr * (rr + 1) / 2 + r] = Wc[rr];
  }

  // --- Sigma row r: Sigma[r][b] = dot(W col r, W col b) ---
  float Sig[DD];
  #pragma unroll
  for (int b = 0; b < DD; b++) {
    float s = 0.0f;
    #pragma unroll
    for (int rr = 0; rr < DD; rr++)
      s = fmaf(Wc[rr], __shfl(Wc[rr], b, 16), s);
    Sig[b] = s;
  }
  #pragma unroll
  for (int b = 0; b < DD; b++) if (b <= r) sSig[k][r * DD + b] = Sig[b];

  // --- rhs[r] = dot(Sigma row r, mu_k) ---
  {
    float muv = mu[k * DD + r];
    float s = 0.0f;
    #pragma unroll
    for (int b = 0; b < DD; b++)
      s = fmaf(Sig[b], __shfl(muv, b, 16), s);
    sR[k * DD + r] = s;
    ((float*)(wsb + WS_RHS))[k * DD + r] = s;
  }

  __syncthreads();

  // ================= phase B: per-pair constants (1 thread / pair) =================
  const int i = tid >> 4, j = tid & 15;
  if (j < i) return;

  float Mx[NPAIR];
  // Ssum = Sigma_i + Sigma_j (packed lower)
  #pragma unroll
  for (int a = 0; a < DD; a++)
    #pragma unroll
    for (int c = 0; c <= a; c++)
      Mx[a * (a + 1) / 2 + c] = sSig[i][a * DD + c] + sSig[j][a * DD + c];

  float ldetS = 0.0f;
  #pragma unroll
  for (int c = 0; c < DD; c++) {
    float s = Mx[c * (c + 1) / 2 + c];
    #pragma unroll
    for (int m = 0; m < c; m++) { float v = Mx[c * (c + 1) / 2 + m]; s = fmaf(-v, v, s); }
    float dd = sqrtf(s);
    Mx[c * (c + 1) / 2 + c] = dd;
    ldetS += __logf(dd);
    float inv = 1.0f / dd;
    #pragma unroll
    for (int rr = c + 1; rr < DD; rr++) {
      float u = Mx[rr * (rr + 1) / 2 + c];
      #pragma unroll
      for (int m = 0; m < c; m++)
        u = fmaf(-Mx[rr * (rr + 1) / 2 + m], Mx[c * (c + 1) / 2 + m], u);
      Mx[rr * (rr + 1) / 2 + c] = u * inv;
    }
  }
  ldetS *= 2.0f;

  float yv[DD]; float cq = 0.0f;
  #pragma unroll
  for (int rr = 0; rr < DD; rr++) {
    float s = sR[i * DD + rr] + sR[j * DD + rr];
    #pragma unroll
    for (int m = 0; m < rr; m++) s = fmaf(-Mx[rr * (rr + 1) / 2 + m], yv[m], s);
    float v = s / Mx[rr * (rr + 1) / 2 + rr];
    yv[rr] = v; cq = fmaf(v, v, cq);
  }

  // Asum = A_i + A_j
  #pragma unroll
  for (int a = 0; a < DD; a++)
    #pragma unroll
    for (int c = 0; c <= a; c++)
      Mx[a * (a + 1) / 2 + c] = sA[i][a * DD + c] + sA[j][a * DD + c];

  float ldetA = 0.0f;
  #pragma unroll
  for (int c = 0; c < DD; c++) {
    float s = Mx[c * (c + 1) / 2 + c];
    #pragma unroll
    for (int m = 0; m < c; m++) { float v = Mx[c * (c + 1) / 2 + m]; s = fmaf(-v, v, s); }
    float dd = sqrtf(s);
    Mx[c * (c + 1) / 2 + c] = dd;
    ldetA += __logf(dd);
    float inv = 1.0f / dd;
    #pragma unroll
    for (int rr = c + 1; rr < DD; rr++) {
      float u = Mx[rr * (rr + 1) / 2 + c];
      #pragma unroll
      for (int m = 0; m < c; m++)
        u = fmaf(-Mx[rr * (rr + 1) / 2 + m], Mx[c * (c + 1) / 2 + m], u);
      Mx[rr * (rr + 1) / 2 + c] = u * inv;
    }
  }
  ldetA *= 2.0f;

  float q = 0.0f;
  #pragma unroll
  for (int rr = 0; rr < DD; rr++) {
    float s = mu[i * DD + rr] - mu[j * DD + rr];
    #pragma unroll
    for (int m = 0; m < rr; m++) s = fmaf(-Mx[rr * (rr + 1) / 2 + m], yv[m], s);
    float v = s / Mx[rr * (rr + 1) / 2 + rr];
    yv[rr] = v; q = fmaf(v, v, q);
  }

  float lC = -0.5f * q - 0.5f * ldetA + 0.5f * ldetS - (float)DD * LN2PI
             + __logf(wts[i]) + __logf(wts[j]) - 0.5f * cq;
  if (i < j) lC += 0.69314718056f;   // symmetric pair counted twice

  int p = i * DD - (i * (i - 1)) / 2 + (j - i);
  ((float*)(wsb + WS_LCS))[p] = lC;
}

// ---------------- main kernel: per-sample log pdf ----------------
__global__ __launch_bounds__(64) void gm_main(const float* __restrict__ X,
                                              char* __restrict__ wsb) {
  __shared__ float sW[KK * NPAIR];
  __shared__ float sR[KK * DD];
  __shared__ float sLC[NPAIR];
  __shared__ float sE[64][17];

  int tid = threadIdx.x;
  {
    const float* Wp = (const float*)(wsb + WS_WP);
    const float* Rf = (const float*)(wsb + WS_RHS);
    const float* lc = (const float*)(wsb + WS_LCS);
    for (int idx = tid; idx < KK * NPAIR; idx += 64) sW[idx] = Wp[idx];
    for (int idx = tid; idx < KK * DD; idx += 64) sR[idx] = Rf[idx];
    for (int idx = tid; idx < NPAIR; idx += 64) sLC[idx] = lc[idx];
  }
  __syncthreads();

  int n = blockIdx.x * 64 + tid;
  const float4* Xp = (const float4*)(X + (size_t)n * DD);
  float4 a0 = Xp[0], a1 = Xp[1], a2 = Xp[2], a3 = Xp[3];
  float x[16] = {a0.x, a0.y, a0.z, a0.w, a1.x, a1.y, a1.z, a1.w,
                 a2.x, a2.y, a2.z, a2.w, a3.x, a3.y, a3.z, a3.w};

  for (int k = 0; k < KK; k++) {
    const float* Wk = &sW[k * NPAIR];
    float g = 0.0f;
    #pragma unroll
    for (int r = 0; r < DD; r++) {
      float y = 0.0f;
      const int base = r * (r + 1) / 2;
      #pragma unroll
      for (int c = 0; c <= r; c++) y = fmaf(Wk[base + c], x[c], y);
      g = fmaf(y, y, g);
    }
    float h = 0.0f;
    #pragma unroll
    for (int d = 0; d < DD; d++) h = fmaf(sR[k * DD + d], x[d], h);
    sE[tid][k] = fmaf(-0.5f, g, h);   // e_k = h - g/2
  }

  // pass 1: max exponent
  float T = -3.0e38f;
  {
    int p = 0;
    for (int i = 0; i < KK; i++) {
      float ei = sE[tid][i];
      for (int j = i; j < KK; j++) {
        float t = sLC[p++] + ei + sE[tid][j];
        T = fmaxf(T, t);
      }
    }
  }
  // pass 2: sum
  float s = 0.0f;
  {
    int p = 0;
    for (int i = 0; i < KK; i++) {
      float ei = sE[tid][i] - T;
      for (int j = i; j < KK; j++) {
        s += __expf(sLC[p++] + ei + sE[tid][j]);
      }
    }
  }
  float lp = T + __logf(s);

  double d = (double)lp;
  #pragma unroll
  for (int off = 32; off > 0; off >>= 1) d += __shfl_down(d, off);
  if (tid == 0) ((double*)(wsb + WS_PART))[blockIdx.x] = d;
}

// ---------------- finalize ----------------
__global__ void gm_fin(const double* __restrict__ part, float* __restrict__ out) {
  int t = threadIdx.x;
  double v = part[t];
  #pragma unroll
  for (int off = 32; off > 0; off >>= 1) v += __shfl_down(v, off);
  __shared__ double r4[4];
  if ((t & 63) == 0) r4[t >> 6] = v;
  __syncthreads();
  if (t == 0) out[0] = (float)((r4[0] + r4[1] + r4[2] + r4[3]) * (1.0 / 16384.0));
}

extern "C" void kernel_launch(void* const* d_in, const int* in_sizes, int n_in,
                              void* d_out, int out_size, void* d_ws, size_t ws_size,
                              hipStream_t stream) {
  const float* X   = (const float*)d_in[0];
  const float* mu  = (const float*)d_in[1];
  const float* L   = (const float*)d_in[2];
  const float* wts = (const float*)d_in[3];
  char* wsb = (char*)d_ws;
  if (ws_size < WS_END) return;

  hipLaunchKernelGGL(gm_pre, dim3(1), dim3(256), 0, stream, mu, L, wts, wsb);
  hipLaunchKernelGGL(gm_main, dim3(NTOT / 64), dim3(64), 0, stream, X, wsb);
  hipLaunchKernelGGL(gm_fin, dim3(1), dim3(256), 0, stream,
                     (const double*)(wsb + WS_PART), (float*)d_out);
}

// Round 4
// 47.298 us; speedup vs baseline: 3.1406x; 1.0749x over previous
//
#include <hip/hip_runtime.h>
#include <math.h>

#define NTOT 16384
#define KK 16
#define DD 16
#define NPAIR 136   // upper-tri incl diag of 16x16

// ---- ws layout (bytes), total exactly 45088 ----
#define WS_RHS   0          // float[256]    rhs_k = Sigma_k mu_k         pre->pair,main
#define WS_WP    1024       // float[16*136] W_k packed lower             pre->main
#define WS_LCS   9728       // float[136]    lC packed upper (+ln2)       pair->main
#define WS_SIG   10272      // float[16*256] Sigma_k FULL                 pre->pair
#define WS_AF    26656      // float[16*256] A_k FULL                     pre->pair
#define WS_PART  43040      // double[256]   block partials               main->fin
#define WS_END   45088

#define LN2PI 1.8378770664093454836f

// ---------------- phase A: per-component, lane-parallel ----------------
// 16 lanes per component; lane r holds row r (or col r) of 16x16 matrices.
__global__ __launch_bounds__(256) void gm_pre(const float* __restrict__ mu,
                                              const float* __restrict__ L,
                                              char* __restrict__ wsb) {
  const int tid = threadIdx.x;
  const int k = tid >> 4;
  const int r = tid & 15;

  const float* Lk = L + k * DD * DD;
  float Lx[DD];
  #pragma unroll
  for (int b = 0; b < DD; b++) Lx[b] = (b <= r) ? Lk[r * DD + b] : 0.0f;

  // A row r = tril(L)tril(L)^T + I
  float Ar[DD];
  #pragma unroll
  for (int c = 0; c < DD; c++) {
    float s = (r == c) ? 1.0f : 0.0f;
    #pragma unroll
    for (int b = 0; b <= c; b++)
      s = fmaf(Lx[b], __shfl(Lx[b], c, 16), s);
    Ar[c] = s;
  }
  {
    float* Aout = (float*)(wsb + WS_AF) + k * DD * DD;
    #pragma unroll
    for (int c = 0; c < DD; c++) Aout[r * DD + c] = Ar[c];
  }

  // Cholesky A = G G^T (lane r = row r of G)
  float Gr[DD];
  #pragma unroll
  for (int m = 0; m < DD; m++) Gr[m] = 0.0f;
  #pragma unroll
  for (int c = 0; c < DD; c++) {
    float u = Ar[c];
    #pragma unroll
    for (int m = 0; m < c; m++)
      u = fmaf(-Gr[m], __shfl(Gr[m], c, 16), u);
    float d = sqrtf(__shfl(u, c, 16));
    float val = (r == c) ? d : u / d;
    if (r >= c) Gr[c] = val;
  }

  // W = G^{-1}, lane r holds COLUMN r of W
  float Wc[DD];
  #pragma unroll
  for (int m = 0; m < DD; m++) Wc[m] = 0.0f;
  #pragma unroll
  for (int rr = 0; rr < DD; rr++) {
    float s = (r == rr) ? 1.0f : 0.0f;
    #pragma unroll
    for (int m = 0; m < rr; m++)
      s = fmaf(-__shfl(Gr[m], rr, 16), Wc[m], s);
    Wc[rr] = s / __shfl(Gr[rr], rr, 16);
  }
  {
    float* Wout = (float*)(wsb + WS_WP) + k * NPAIR;
    #pragma unroll
    for (int rr = 0; rr < DD; rr++)
      if (rr >= r) Wout[rr * (rr + 1) / 2 + r] = Wc[rr];
  }

  // Sigma row r (full) = dot(W col r, W col b)
  float Sig[DD];
  #pragma unroll
  for (int b = 0; b < DD; b++) {
    float s = 0.0f;
    #pragma unroll
    for (int rr = 0; rr < DD; rr++)
      s = fmaf(Wc[rr], __shfl(Wc[rr], b, 16), s);
    Sig[b] = s;
  }
  {
    float* Sout = (float*)(wsb + WS_SIG) + k * DD * DD;
    #pragma unroll
    for (int b = 0; b < DD; b++) Sout[r * DD + b] = Sig[b];
  }

  // rhs[r] = dot(Sigma row r, mu_k)
  {
    float muv = mu[k * DD + r];
    float s = 0.0f;
    #pragma unroll
    for (int b = 0; b < DD; b++)
      s = fmaf(Sig[b], __shfl(muv, b, 16), s);
    ((float*)(wsb + WS_RHS))[k * DD + r] = s;
  }
}

// ---------------- per-pair constants, lane-parallel (16 lanes / pair) ----------------
__global__ __launch_bounds__(256) void gm_pair(const float* __restrict__ mu,
                                               const float* __restrict__ wts,
                                               char* __restrict__ wsb) {
  const int tid = threadIdx.x;
  const int g = (blockIdx.x << 4) + (tid >> 4);   // pair index
  const int r = tid & 15;
  if (g >= NPAIR) return;
  int i = 0, rem = g;
  while (rem >= (KK - i)) { rem -= (KK - i); i++; }
  const int j = i + rem;

  const float* Sf = (const float*)(wsb + WS_SIG);
  const float* Af = (const float*)(wsb + WS_AF);
  const float* Rf = (const float*)(wsb + WS_RHS);

  float Mr[DD], Gr[DD];

  // ===== Ssum = Sigma_i + Sigma_j =====
  #pragma unroll
  for (int c = 0; c < DD; c++)
    Mr[c] = Sf[i * 256 + r * DD + c] + Sf[j * 256 + r * DD + c];

  float ldS = 0.0f, mydinv = 0.0f;
  #pragma unroll
  for (int m = 0; m < DD; m++) Gr[m] = 0.0f;
  #pragma unroll
  for (int c = 0; c < DD; c++) {
    float u = Mr[c];
    #pragma unroll
    for (int m = 0; m < c; m++)
      u = fmaf(-Gr[m], __shfl(Gr[m], c, 16), u);
    float d2 = __shfl(u, c, 16);
    ldS += __logf(d2);                 // every lane accumulates full log-det
    float d = sqrtf(d2);
    float dinv = 1.0f / d;
    if (r == c) mydinv = dinv;
    float val = (r == c) ? d : u * dinv;
    if (r >= c) Gr[c] = val;
  }
  // solve G y = rhs_i + rhs_j ; cq = |y|^2
  float cq = 0.0f;
  {
    float acc = Rf[i * DD + r] + Rf[j * DD + r];
    #pragma unroll
    for (int m = 0; m < DD; m++) {
      float ym = __shfl(acc, m, 16) * __shfl(mydinv, m, 16);
      cq = fmaf(ym, ym, cq);
      if (r > m) acc = fmaf(-Gr[m], ym, acc);
    }
  }

  // ===== Asum = A_i + A_j =====
  #pragma unroll
  for (int c = 0; c < DD; c++)
    Mr[c] = Af[i * 256 + r * DD + c] + Af[j * 256 + r * DD + c];

  float ldA = 0.0f, mydinvA = 0.0f;
  #pragma unroll
  for (int m = 0; m < DD; m++) Gr[m] = 0.0f;
  #pragma unroll
  for (int c = 0; c < DD; c++) {
    float u = Mr[c];
    #pragma unroll
    for (int m = 0; m < c; m++)
      u = fmaf(-Gr[m], __shfl(Gr[m], c, 16), u);
    float d2 = __shfl(u, c, 16);
    ldA += __logf(d2);
    float d = sqrtf(d2);
    float dinv = 1.0f / d;
    if (r == c) mydinvA = dinv;
    float val = (r == c) ? d : u * dinv;
    if (r >= c) Gr[c] = val;
  }
  // solve G y = mu_i - mu_j ; q = |y|^2
  float q = 0.0f;
  {
    float acc = mu[i * DD + r] - mu[j * DD + r];
    #pragma unroll
    for (int m = 0; m < DD; m++) {
      float ym = __shfl(acc, m, 16) * __shfl(mydinvA, m, 16);
      q = fmaf(ym, ym, q);
      if (r > m) acc = fmaf(-Gr[m], ym, acc);
    }
  }

  if (r == 0) {
    float lC = -0.5f * q - 0.5f * ldA + 0.5f * ldS - (float)DD * LN2PI
               + __logf(wts[i]) + __logf(wts[j]) - 0.5f * cq;
    if (i < j) lC += 0.69314718056f;   // symmetric pair counted twice
    ((float*)(wsb + WS_LCS))[g] = lC;
  }
}

// ---------------- main kernel: per-sample log pdf ----------------
__global__ __launch_bounds__(64) void gm_main(const float* __restrict__ X,
                                              char* __restrict__ wsb) {
  __shared__ float sW[KK * NPAIR];
  __shared__ float sR[KK * DD];
  __shared__ float sLC[NPAIR];

  int tid = threadIdx.x;
  {
    const float* Wp = (const float*)(wsb + WS_WP);
    const float* Rf = (const float*)(wsb + WS_RHS);
    const float* lc = (const float*)(wsb + WS_LCS);
    for (int idx = tid; idx < KK * NPAIR; idx += 64) sW[idx] = Wp[idx];
    for (int idx = tid; idx < KK * DD; idx += 64) sR[idx] = Rf[idx];
    for (int idx = tid; idx < NPAIR; idx += 64) sLC[idx] = lc[idx];
  }
  __syncthreads();

  int n = blockIdx.x * 64 + tid;
  const float4* Xp = (const float4*)(X + (size_t)n * DD);
  float4 a0 = Xp[0], a1 = Xp[1], a2 = Xp[2], a3 = Xp[3];
  float x[16] = {a0.x, a0.y, a0.z, a0.w, a1.x, a1.y, a1.z, a1.w,
                 a2.x, a2.y, a2.z, a2.w, a3.x, a3.y, a3.z, a3.w};

  float e[KK];                 // register-resident (k-loop fully unrolled)
  #pragma unroll
  for (int k = 0; k < KK; k++) {
    const float* Wk = &sW[k * NPAIR];
    float g = 0.0f;
    #pragma unroll
    for (int r = 0; r < DD; r++) {
      float y = 0.0f;
      #pragma unroll
      for (int c = 0; c <= r; c++) y = fmaf(Wk[r * (r + 1) / 2 + c], x[c], y);
      g = fmaf(y, y, g);
    }
    float h = 0.0f;
    #pragma unroll
    for (int d = 0; d < DD; d++) h = fmaf(sR[k * DD + d], x[d], h);
    e[k] = fmaf(-0.5f, g, h);
  }

  // pass 1: max exponent (all indices static)
  float T = -3.0e38f;
  #pragma unroll
  for (int i = 0; i < KK; i++) {
    #pragma unroll
    for (int j = i; j < KK; j++) {
      const int p = i * KK - (i * (i - 1)) / 2 + (j - i);
      T = fmaxf(T, sLC[p] + e[i] + e[j]);
    }
  }
  // pass 2: sum
  float s = 0.0f;
  #pragma unroll
  for (int i = 0; i < KK; i++) {
    #pragma unroll
    for (int j = i; j < KK; j++) {
      const int p = i * KK - (i * (i - 1)) / 2 + (j - i);
      s += __expf(sLC[p] + (e[i] + e[j]) - T);
    }
  }
  float lp = T + __logf(s);

  double d = (double)lp;
  #pragma unroll
  for (int off = 32; off > 0; off >>= 1) d += __shfl_down(d, off);
  if (tid == 0) ((double*)(wsb + WS_PART))[blockIdx.x] = d;
}

// ---------------- finalize ----------------
__global__ void gm_fin(const double* __restrict__ part, float* __restrict__ out) {
  int t = threadIdx.x;
  double v = part[t];
  #pragma unroll
  for (int off = 32; off > 0; off >>= 1) v += __shfl_down(v, off);
  __shared__ double r4[4];
  if ((t & 63) == 0) r4[t >> 6] = v;
  __syncthreads();
  if (t == 0) out[0] = (float)((r4[0] + r4[1] + r4[2] + r4[3]) * (1.0 / 16384.0));
}

extern "C" void kernel_launch(void* const* d_in, const int* in_sizes, int n_in,
                              void* d_out, int out_size, void* d_ws, size_t ws_size,
                              hipStream_t stream) {
  const float* X   = (const float*)d_in[0];
  const float* mu  = (const float*)d_in[1];
  const float* L   = (const float*)d_in[2];
  const float* wts = (const float*)d_in[3];
  char* wsb = (char*)d_ws;
  if (ws_size < WS_END) return;

  hipLaunchKernelGGL(gm_pre,  dim3(1), dim3(256), 0, stream, mu, L, wsb);
  hipLaunchKernelGGL(gm_pair, dim3(9), dim3(256), 0, stream, mu, wts, wsb);
  hipLaunchKernelGGL(gm_main, dim3(NTOT / 64), dim3(64), 0, stream, X, wsb);
  hipLaunchKernelGGL(gm_fin,  dim3(1), dim3(256), 0, stream,
                     (const double*)(wsb + WS_PART), (float*)d_out);
}

// Round 5
// 38.065 us; speedup vs baseline: 3.9023x; 1.2426x over previous
//
#include <hip/hip_runtime.h>
#include <math.h>

#define NTOT 16384
#define KK 16
#define DD 16
#define NPAIR 136   // upper-tri incl diag of 16x16

// ---- ws layout (bytes) ----
#define WS_RHS   0          // float[256]     rhs_k = Sigma_k mu_k        pre->pair,main
#define WS_WP    1024       // float[16*137]  W_k packed lower, stride137 pre->main
#define WS_LCS   9792       // float[136]     lC packed upper (+ln2)      pair->main
#define WS_SIG   10336      // float[16*256]  Sigma_k FULL                pre->pair
#define WS_AF    26720      // float[16*256]  A_k FULL                    pre->pair
#define WS_PART  10336      // double[1024]   block partials (ALIASES SIG; written after pair consumed it)
#define WS_END   43104

#define LN2PI 1.8378770664093454836f

// ---------------- phase A: per-component, lane-parallel ----------------
__global__ __launch_bounds__(256) void gm_pre(const float* __restrict__ mu,
                                              const float* __restrict__ L,
                                              char* __restrict__ wsb) {
  const int tid = threadIdx.x;
  const int k = tid >> 4;
  const int r = tid & 15;

  const float* Lk = L + k * DD * DD;
  float Lx[DD];
  #pragma unroll
  for (int b = 0; b < DD; b++) Lx[b] = (b <= r) ? Lk[r * DD + b] : 0.0f;

  // A row r = tril(L)tril(L)^T + I
  float Ar[DD];
  #pragma unroll
  for (int c = 0; c < DD; c++) {
    float s = (r == c) ? 1.0f : 0.0f;
    #pragma unroll
    for (int b = 0; b <= c; b++)
      s = fmaf(Lx[b], __shfl(Lx[b], c, 16), s);
    Ar[c] = s;
  }
  {
    float* Aout = (float*)(wsb + WS_AF) + k * DD * DD;
    #pragma unroll
    for (int c = 0; c < DD; c++) Aout[r * DD + c] = Ar[c];
  }

  // Cholesky A = G G^T (lane r = row r of G)
  float Gr[DD];
  #pragma unroll
  for (int m = 0; m < DD; m++) Gr[m] = 0.0f;
  #pragma unroll
  for (int c = 0; c < DD; c++) {
    float u = Ar[c];
    #pragma unroll
    for (int m = 0; m < c; m++)
      u = fmaf(-Gr[m], __shfl(Gr[m], c, 16), u);
    float d = sqrtf(__shfl(u, c, 16));
    float val = (r == c) ? d : u / d;
    if (r >= c) Gr[c] = val;
  }

  // W = G^{-1}, lane r holds COLUMN r of W
  float Wc[DD];
  #pragma unroll
  for (int m = 0; m < DD; m++) Wc[m] = 0.0f;
  #pragma unroll
  for (int rr = 0; rr < DD; rr++) {
    float s = (r == rr) ? 1.0f : 0.0f;
    #pragma unroll
    for (int m = 0; m < rr; m++)
      s = fmaf(-__shfl(Gr[m], rr, 16), Wc[m], s);
    Wc[rr] = s / __shfl(Gr[rr], rr, 16);
  }
  {
    float* Wout = (float*)(wsb + WS_WP) + k * 137;   // stride 137 floats
    #pragma unroll
    for (int rr = 0; rr < DD; rr++)
      if (rr >= r) Wout[rr * (rr + 1) / 2 + r] = Wc[rr];
  }

  // Sigma row r (full)
  float Sig[DD];
  #pragma unroll
  for (int b = 0; b < DD; b++) {
    float s = 0.0f;
    #pragma unroll
    for (int rr = 0; rr < DD; rr++)
      s = fmaf(Wc[rr], __shfl(Wc[rr], b, 16), s);
    Sig[b] = s;
  }
  {
    float* Sout = (float*)(wsb + WS_SIG) + k * DD * DD;
    #pragma unroll
    for (int b = 0; b < DD; b++) Sout[r * DD + b] = Sig[b];
  }

  // rhs[r] = dot(Sigma row r, mu_k)
  {
    float muv = mu[k * DD + r];
    float s = 0.0f;
    #pragma unroll
    for (int b = 0; b < DD; b++)
      s = fmaf(Sig[b], __shfl(muv, b, 16), s);
    ((float*)(wsb + WS_RHS))[k * DD + r] = s;
  }
}

// ---------------- per-pair constants, lane-parallel (16 lanes / pair) ----------------
__global__ __launch_bounds__(256) void gm_pair(const float* __restrict__ mu,
                                               const float* __restrict__ wts,
                                               char* __restrict__ wsb) {
  const int tid = threadIdx.x;
  const int g = (blockIdx.x << 4) + (tid >> 4);
  const int r = tid & 15;
  if (g >= NPAIR) return;
  int i = 0, rem = g;
  while (rem >= (KK - i)) { rem -= (KK - i); i++; }
  const int j = i + rem;

  const float* Sf = (const float*)(wsb + WS_SIG);
  const float* Af = (const float*)(wsb + WS_AF);
  const float* Rf = (const float*)(wsb + WS_RHS);

  float Mr[DD], Gr[DD];

  // ===== Ssum =====
  #pragma unroll
  for (int c = 0; c < DD; c++)
    Mr[c] = Sf[i * 256 + r * DD + c] + Sf[j * 256 + r * DD + c];

  float ldS = 0.0f, mydinv = 0.0f;
  #pragma unroll
  for (int m = 0; m < DD; m++) Gr[m] = 0.0f;
  #pragma unroll
  for (int c = 0; c < DD; c++) {
    float u = Mr[c];
    #pragma unroll
    for (int m = 0; m < c; m++)
      u = fmaf(-Gr[m], __shfl(Gr[m], c, 16), u);
    float d2 = __shfl(u, c, 16);
    ldS += __logf(d2);
    float d = sqrtf(d2);
    float dinv = 1.0f / d;
    if (r == c) mydinv = dinv;
    float val = (r == c) ? d : u * dinv;
    if (r >= c) Gr[c] = val;
  }
  float cq = 0.0f;
  {
    float acc = Rf[i * DD + r] + Rf[j * DD + r];
    #pragma unroll
    for (int m = 0; m < DD; m++) {
      float ym = __shfl(acc, m, 16) * __shfl(mydinv, m, 16);
      cq = fmaf(ym, ym, cq);
      if (r > m) acc = fmaf(-Gr[m], ym, acc);
    }
  }

  // ===== Asum =====
  #pragma unroll
  for (int c = 0; c < DD; c++)
    Mr[c] = Af[i * 256 + r * DD + c] + Af[j * 256 + r * DD + c];

  float ldA = 0.0f, mydinvA = 0.0f;
  #pragma unroll
  for (int m = 0; m < DD; m++) Gr[m] = 0.0f;
  #pragma unroll
  for (int c = 0; c < DD; c++) {
    float u = Mr[c];
    #pragma unroll
    for (int m = 0; m < c; m++)
      u = fmaf(-Gr[m], __shfl(Gr[m], c, 16), u);
    float d2 = __shfl(u, c, 16);
    ldA += __logf(d2);
    float d = sqrtf(d2);
    float dinv = 1.0f / d;
    if (r == c) mydinvA = dinv;
    float val = (r == c) ? d : u * dinv;
    if (r >= c) Gr[c] = val;
  }
  float q = 0.0f;
  {
    float acc = mu[i * DD + r] - mu[j * DD + r];
    #pragma unroll
    for (int m = 0; m < DD; m++) {
      float ym = __shfl(acc, m, 16) * __shfl(mydinvA, m, 16);
      q = fmaf(ym, ym, q);
      if (r > m) acc = fmaf(-Gr[m], ym, acc);
    }
  }

  if (r == 0) {
    float lC = -0.5f * q - 0.5f * ldA + 0.5f * ldS - (float)DD * LN2PI
               + __logf(wts[i]) + __logf(wts[j]) - 0.5f * cq;
    if (i < j) lC += 0.69314718056f;
    ((float*)(wsb + WS_LCS))[g] = lC;
  }
}

// ---------------- main kernel: 16 lanes per sample ----------------
// Block = 256 threads = 16 samples. Lane r of group s computes e_r for sample s.
__global__ __launch_bounds__(256) void gm_main(const float* __restrict__ X,
                                               char* __restrict__ wsb) {
  __shared__ float sW[KK * 137];          // W_k packed lower, stride 137 -> conflict-free
  __shared__ float sR[KK * 17];           // rhs, stride 17
  __shared__ float sLC[NPAIR];
  __shared__ unsigned char sIJ[NPAIR];
  __shared__ float sX[256];               // 16 samples x 16 dims
  __shared__ float sE[16 * 17];           // e[k] per sample, stride 17
  __shared__ double sD[16];

  const int tid = threadIdx.x;
  const int s = tid >> 4;     // sample within block
  const int r = tid & 15;     // component index

  // ---- stage constants ----
  {
    const float* Wp = (const float*)(wsb + WS_WP);
    for (int idx = tid; idx < KK * 137; idx += 256) sW[idx] = Wp[idx];
    const float* Rf = (const float*)(wsb + WS_RHS);
    if (tid < 256) sR[(tid >> 4) * 17 + (tid & 15)] = Rf[tid];
    const float* lc = (const float*)(wsb + WS_LCS);
    if (tid < NPAIR) {
      sLC[tid] = lc[tid];
      int i = 0, rem = tid;
      while (rem >= (KK - i)) { rem -= (KK - i); i++; }
      sIJ[tid] = (unsigned char)((i << 4) | (i + rem));
    }
    if (tid < 64)
      ((float4*)sX)[tid] = ((const float4*)(X + (size_t)blockIdx.x * 256))[tid];
  }
  __syncthreads();

  // ---- x into registers (broadcast within group; 2-way LDS alias = free) ----
  float x[DD];
  {
    float4 b0 = ((const float4*)sX)[s * 4 + 0];
    float4 b1 = ((const float4*)sX)[s * 4 + 1];
    float4 b2 = ((const float4*)sX)[s * 4 + 2];
    float4 b3 = ((const float4*)sX)[s * 4 + 3];
    x[0]=b0.x; x[1]=b0.y; x[2]=b0.z; x[3]=b0.w;
    x[4]=b1.x; x[5]=b1.y; x[6]=b1.z; x[7]=b1.w;
    x[8]=b2.x; x[9]=b2.y; x[10]=b2.z; x[11]=b2.w;
    x[12]=b3.x; x[13]=b3.y; x[14]=b3.z; x[15]=b3.w;
  }

  // ---- e_r = h - g/2 for component r ----
  {
    const float* Wk = &sW[r * 137];
    float g = 0.0f;
    #pragma unroll
    for (int rr = 0; rr < DD; rr++) {
      float y = 0.0f;
      #pragma unroll
      for (int c = 0; c <= rr; c++) y = fmaf(Wk[rr * (rr + 1) / 2 + c], x[c], y);
      g = fmaf(y, y, g);
    }
    float h = 0.0f;
    #pragma unroll
    for (int d = 0; d < DD; d++) h = fmaf(sR[r * 17 + d], x[d], h);
    sE[s * 17 + r] = fmaf(-0.5f, g, h);
  }
  __syncthreads();

  // ---- pairs: 8-9 per lane; two-pass log-sum-exp with width-16 reductions ----
  float val[9];
  float T = -3.0e38f;
  #pragma unroll
  for (int t = 0; t < 9; t++) {
    int p = t * 16 + r;
    if (t < 8 || r < 8) {
      int ij = sIJ[p];
      val[t] = sLC[p] + sE[s * 17 + (ij >> 4)] + sE[s * 17 + (ij & 15)];
    } else {
      val[t] = -3.0e38f;
    }
    T = fmaxf(T, val[t]);
  }
  #pragma unroll
  for (int w = 1; w < 16; w <<= 1) T = fmaxf(T, __shfl_xor(T, w, 16));

  float sum = 0.0f;
  #pragma unroll
  for (int t = 0; t < 9; t++) sum += __expf(val[t] - T);
  #pragma unroll
  for (int w = 1; w < 16; w <<= 1) sum += __shfl_xor(sum, w, 16);

  if (r == 0) sD[s] = (double)(T + __logf(sum));
  __syncthreads();
  if (tid == 0) {
    double acc = 0.0;
    #pragma unroll
    for (int m = 0; m < 16; m++) acc += sD[m];
    ((double*)(wsb + WS_PART))[blockIdx.x] = acc;
  }
}

// ---------------- finalize: reduce 1024 partials ----------------
__global__ __launch_bounds__(256) void gm_fin(const double* __restrict__ part,
                                              float* __restrict__ out) {
  int t = threadIdx.x;
  double v = part[t] + part[t + 256] + part[t + 512] + part[t + 768];
  #pragma unroll
  for (int off = 32; off > 0; off >>= 1) v += __shfl_down(v, off);
  __shared__ double r4[4];
  if ((t & 63) == 0) r4[t >> 6] = v;
  __syncthreads();
  if (t == 0) out[0] = (float)((r4[0] + r4[1] + r4[2] + r4[3]) * (1.0 / 16384.0));
}

extern "C" void kernel_launch(void* const* d_in, const int* in_sizes, int n_in,
                              void* d_out, int out_size, void* d_ws, size_t ws_size,
                              hipStream_t stream) {
  const float* X   = (const float*)d_in[0];
  const float* mu  = (const float*)d_in[1];
  const float* L   = (const float*)d_in[2];
  const float* wts = (const float*)d_in[3];
  char* wsb = (char*)d_ws;
  if (ws_size < WS_END) return;

  hipLaunchKernelGGL(gm_pre,  dim3(1), dim3(256), 0, stream, mu, L, wsb);
  hipLaunchKernelGGL(gm_pair, dim3(9), dim3(256), 0, stream, mu, wts, wsb);
  hipLaunchKernelGGL(gm_main, dim3(NTOT / 16), dim3(256), 0, stream, X, wsb);
  hipLaunchKernelGGL(gm_fin,  dim3(1), dim3(256), 0, stream,
                     (const double*)(wsb + WS_PART), (float*)d_out);
}